// Round 7
// baseline (338.866 us; speedup 1.0000x reference)
//
#include <hip/hip_runtime.h>
#include <hip/hip_cooperative_groups.h>
#include <cmath>

namespace cg = cooperative_groups;

// Problem constants (fixed by the reference)
constexpr int T_DIM = 4096;
constexpr int H_DIM = 1024;
constexpr int E_DIM = 8;
constexpr int I_DIM = 512;   // 4096 / 8
constexpr int V_DIM = 32000;

typedef _Float16 half_t;
typedef __attribute__((ext_vector_type(8))) _Float16 halfx8;
typedef __attribute__((ext_vector_type(4))) _Float16 halfx4;
typedef __attribute__((ext_vector_type(4))) float floatx4;

// async global->LDS, 16 B per lane; LDS dest is wave-uniform base + lane*16
#define GLOAD16(g, l)                                                        \
    __builtin_amdgcn_global_load_lds(                                        \
        (const __attribute__((address_space(1))) void*)(g),                  \
        (__attribute__((address_space(3))) void*)(l), 16, 0, 0)

// ---------------------------------------------------------------------------
// Workspace layout (bytes)
// ---------------------------------------------------------------------------
constexpr int  CNT_STRIDE  = 16;                                          // ints
constexpr size_t OFF_COUNTS = 0;                                          // E*16 ints (512 B)
constexpr size_t OFF_EID    = 1024;                                       // T ints (16 KB)
constexpr size_t OFF_TOKL   = OFF_EID + (size_t)T_DIM * 4;                // E*T ints (128 KB)
constexpr size_t OFF_XB     = OFF_TOKL + (size_t)E_DIM * T_DIM * 4;       // T*H f16 (8 MB)
constexpr size_t OFF_GUPT   = OFF_XB + (size_t)T_DIM * H_DIM * 2;         // E*2I*H f16 (16 MB)
constexpr size_t OFF_DOWNT  = OFF_GUPT + (size_t)E_DIM * 2 * I_DIM * H_DIM * 2; // E*H*I f16 (8 MB)
constexpr size_t OFF_INTER  = OFF_DOWNT + (size_t)E_DIM * H_DIM * I_DIM * 2;    // T*I f16 (4 MB)

// ---------------------------------------------------------------------------
// ROUND-7: single cooperative launch. Cross-round evidence (R2 161.3 / R4
// 161.4 / R5 158.6 / R6 156.7 despite major structural changes; R1 prep +51
// moved the total exactly +51) => controllable kernel time is ~50us and the
// rest is a fixed per-iteration floor (harness reset dispatches). Within the
// 50us: prep ~35 (routing latency-phase interfering with transpose BW-phase),
// 3 launch gaps ~6-9, scatter ~3, gemms ~10-15. This kernel removes the gaps
// and re-orders the phases dependency-optimally with grid.sync():
//   A: routing alone (pure latency, 4096 items, ~3-4us)
//   B: scatter (8 items, fully hidden) || gup-transpose (2048) || x-convert
//      (512) || down-transpose (1024)  (pure BW, ~20us)
//   C: gemm1 (4096 items, early-exit past count)  [R6 dbuf body, unchanged]
//   D: gemm2 (4096 items)                         [R6 dbuf body, unchanged]
// Grid 512 x 256: 2 blocks/CU guaranteed (49.7KB LDS <= 80KB), so the
// cooperative-launch co-residency check passes. 512 % 8 == 0 keeps the
// item-residue e = it&7 pinned to block-residue = XCD.
// Per-item trailing __syncthreads(): items share LDS sequentially per block.
// ---------------------------------------------------------------------------
__global__ __launch_bounds__(256) void fused_kernel(
    const float* __restrict__ x, const float* __restrict__ gup,
    const float* __restrict__ down, const float* __restrict__ mu,
    const int* __restrict__ token_ids, const float* __restrict__ mu_w,
    half_t* __restrict__ xb, half_t* __restrict__ gupT,
    half_t* __restrict__ downT, int* __restrict__ expert_id,
    int* __restrict__ counts, int* __restrict__ tok_list,
    half_t* __restrict__ inter, float* __restrict__ out)
{
    __shared__ __align__(16) char smraw[49152 + 256];
    const int tid = threadIdx.x;
    const int bx = blockIdx.x;
    const int NB = gridDim.x;              // 512
    const int lane = tid & 63, wv = tid >> 6;
    cg::grid_group grid = cg::this_grid();

    // ======================= Phase A: routing =======================
    {
        float (*part)[E_DIM] = (float (*)[E_DIM])smraw;   // [4][8]
        for (int t = bx; t < T_DIM; t += NB) {
            const float4 m = *(const float4*)&mu[(size_t)t * H_DIM + tid * 4];
            float acc[E_DIM];
#pragma unroll
            for (int e = 0; e < E_DIM; ++e) {
                const float4 w = *(const float4*)&mu_w[e * H_DIM + tid * 4];
                acc[e] = m.x * w.x + m.y * w.y + m.z * w.z + m.w * w.w;
            }
#pragma unroll
            for (int e = 0; e < E_DIM; ++e) {
#pragma unroll
                for (int off = 32; off > 0; off >>= 1)
                    acc[e] += __shfl_down(acc[e], off, 64);
            }
            if (lane == 0) {
#pragma unroll
                for (int e = 0; e < E_DIM; ++e) part[wv][e] = acc[e];
            }
            __syncthreads();
            if (tid == 0) {
                int tk = token_ids[t];
                tk = min(max(tk, 0), V_DIM - 1);
                const int be = tk & (E_DIM - 1);
                float best = -1e30f; int bi = 0;
#pragma unroll
                for (int e = 0; e < E_DIM; ++e) {
                    const float c = part[0][e] + part[1][e] + part[2][e] + part[3][e]
                                  + (e == be ? 10.f : 0.f);
                    if (c > best) { best = c; bi = e; }  // strict > (jnp.argmax)
                }
                expert_id[t] = bi;
            }
            __syncthreads();   // part[] reused next item
        }
    }
    grid.sync();

    // ==== Phase B: scatter(8) + gupT(2048) + convert(512) + downT(1024) ====
    {
        constexpr int N_SC = 8, N_GT = 2048, N_CV = 512, N_DT = 1024;
        for (int it = bx; it < N_SC + N_GT + N_CV + N_DT; it += NB) {
            if (it < N_SC) {
                // ---- scatter for expert e: zero-atomic ballot compaction ----
                const int e = it;
                int* wcnt = (int*)smraw;      // [4]
                int base = 0;
#pragma unroll 1
                for (int r = 0; r < 16; ++r) {
                    const int t = r * 256 + tid;
                    const bool m = (expert_id[t] == e);
                    const unsigned long long mask = __ballot(m);
                    const int wrank = (int)__popcll(mask & ((1ull << lane) - 1ull));
                    if (lane == 0) wcnt[wv] = (int)__popcll(mask);
                    __syncthreads();
                    int pre = 0, tot = 0;
#pragma unroll
                    for (int i = 0; i < 4; ++i) {
                        const int c = wcnt[i];
                        pre += (i < wv) ? c : 0;
                        tot += c;
                    }
                    if (m) tok_list[e * T_DIM + base + pre + wrank] = t;
                    base += tot;
                    __syncthreads();
                }
                if (tid == 0) counts[e * CNT_STRIDE] = base;
                __syncthreads();
            } else if (it < N_SC + N_GT) {
                // ---- gup transpose tile: dst[e][n][k] = (f16) src[e][k][n] ----
                const int tno = it - N_SC;
                const int e = tno >> 8, r = tno & 255;      // 256 tiles/expert
                const int n0 = (r & 15) * 64, k0 = (r >> 4) * 64;
                float (*tile)[65] = (float (*)[65])smraw;   // 16.6KB
                const float* se = gup + (size_t)e * H_DIM * (2 * I_DIM);
                half_t* de = gupT + (size_t)e * (2 * I_DIM) * H_DIM;
                const int c4 = (tid & 15) * 4, r0 = tid >> 4;
#pragma unroll
                for (int p = 0; p < 4; ++p) {
                    const int rr = r0 + p * 16;
                    const float4 v = *(const float4*)&se[(size_t)(k0 + rr) * 1024 + n0 + c4];
                    tile[rr][c4 + 0] = v.x; tile[rr][c4 + 1] = v.y;
                    tile[rr][c4 + 2] = v.z; tile[rr][c4 + 3] = v.w;
                }
                __syncthreads();
#pragma unroll
                for (int p = 0; p < 4; ++p) {
                    const int n = r0 + p * 16;
                    halfx4 h = { (half_t)tile[c4 + 0][n], (half_t)tile[c4 + 1][n],
                                 (half_t)tile[c4 + 2][n], (half_t)tile[c4 + 3][n] };
                    *(halfx4*)&de[(size_t)(n0 + n) * H_DIM + k0 + c4] = h;
                }
                __syncthreads();   // tile reused next item
            } else if (it < N_SC + N_GT + N_CV) {
                // ---- x -> f16 convert: 8192 floats per item ----
                const int idx = it - (N_SC + N_GT);
#pragma unroll
                for (int p = 0; p < 4; ++p) {
                    const size_t i = (size_t)idx * 8192 + p * 2048 + tid * 8;
                    const float4 v0 = *(const float4*)&x[i];
                    const float4 v1 = *(const float4*)&x[i + 4];
                    halfx8 h = { (half_t)v0.x, (half_t)v0.y, (half_t)v0.z, (half_t)v0.w,
                                 (half_t)v1.x, (half_t)v1.y, (half_t)v1.z, (half_t)v1.w };
                    *(halfx8*)&xb[i] = h;
                }
            } else {
                // ---- down transpose tile: dst[e][h][i] = (f16) src[e][i][h] ----
                const int tno = it - (N_SC + N_GT + N_CV);
                const int e = tno >> 7, r = tno & 127;      // 128 tiles/expert
                const int n0 = (r & 15) * 64, k0 = (r >> 4) * 64;  // n over H, k over I
                float (*tile)[65] = (float (*)[65])smraw;
                const float* se = down + (size_t)e * I_DIM * H_DIM;
                half_t* de = downT + (size_t)e * H_DIM * I_DIM;
                const int c4 = (tid & 15) * 4, r0 = tid >> 4;
#pragma unroll
                for (int p = 0; p < 4; ++p) {
                    const int rr = r0 + p * 16;
                    const float4 v = *(const float4*)&se[(size_t)(k0 + rr) * H_DIM + n0 + c4];
                    tile[rr][c4 + 0] = v.x; tile[rr][c4 + 1] = v.y;
                    tile[rr][c4 + 2] = v.z; tile[rr][c4 + 3] = v.w;
                }
                __syncthreads();
#pragma unroll
                for (int p = 0; p < 4; ++p) {
                    const int n = r0 + p * 16;
                    halfx4 h = { (half_t)tile[c4 + 0][n], (half_t)tile[c4 + 1][n],
                                 (half_t)tile[c4 + 2][n], (half_t)tile[c4 + 3][n] };
                    *(halfx4*)&de[(size_t)(n0 + n) * I_DIM + k0 + c4] = h;
                }
                __syncthreads();
            }
        }
    }
    grid.sync();

    // LDS partition for GEMM phases (R6 dbuf layout)
    half_t* const As0 = (half_t*)smraw;                     // 64x64
    half_t* const As1 = (half_t*)(smraw + 8192);
    half_t* const Bs0 = (half_t*)(smraw + 16384);           // 128x64
    half_t* const Bs1 = (half_t*)(smraw + 32768);
    int* const toks = (int*)(smraw + 49152);

    const int w = tid >> 6;
    const int lr = lane >> 3, lc = lane & 7;
    const int wr = w >> 1, wc = w & 1;
    const int fm = lane & 15, q = lane >> 4;
    const int fm7 = fm & 7;
    const floatx4 fzero = {0.f, 0.f, 0.f, 0.f};

    // ======================= Phase C: gemm1 =======================
    // item: e = it&7 (residue-pinned to XCD), n0 = 8 blocks of 64, m0 = 64x64
    for (int it = bx; it < E_DIM * 8 * 64; it += NB) {
        const int e = it & 7;
        const int rest = it >> 3;
        const int n0 = (rest & 7) * 64;
        const int m0 = (rest >> 3) * 64;
        const int count = counts[e * CNT_STRIDE];
        if (m0 >= count) continue;

        if (tid < 64) {
            const int m = m0 + tid;
            toks[tid] = (m < count) ? tok_list[e * T_DIM + m] : -1;
        }
        __syncthreads();

        const half_t* We = gupT + (size_t)e * (2 * I_DIM) * H_DIM;

        const half_t* aptr[2]; const half_t* bptr[4];
        half_t *a0l[2], *a1l[2], *b0l[4], *b1l[4];
#pragma unroll
        for (int j = 0; j < 2; ++j) {                 // A rows [w*16, w*16+16)
            const int r = w * 16 + j * 8 + lr;
            const int cg_ = lc ^ (r & 7);
            const int tk = toks[r];
            aptr[j] = xb + (size_t)(tk < 0 ? 0 : tk) * H_DIM + cg_ * 8;
            const int off = (w * 16 + j * 8) * 64;
            a0l[j] = As0 + off; a1l[j] = As1 + off;
        }
#pragma unroll
        for (int j = 0; j < 4; ++j) {                 // B rows [w*32, w*32+32)
            const int n = w * 32 + j * 8 + lr;
            const int col = (n < 64) ? (n0 + n) : (I_DIM + n0 + (n - 64));
            const int cg_ = lc ^ (n & 7);
            bptr[j] = We + (size_t)col * H_DIM + cg_ * 8;
            const int off = (w * 32 + j * 8) * 64;
            b0l[j] = Bs0 + off; b1l[j] = Bs1 + off;
        }

        floatx4 accg[2][2], accu[2][2];
#pragma unroll
        for (int i = 0; i < 2; ++i)
#pragma unroll
            for (int j = 0; j < 2; ++j) { accg[i][j] = fzero; accu[i][j] = fzero; }

        auto mfma_phase = [&](const half_t* A_, const half_t* B_) {
#pragma unroll
            for (int ks = 0; ks < 2; ++ks) {
                const int swz = ((ks * 4 + q) ^ fm7) * 8;
                const halfx8 a0 = *(const halfx8*)&A_[(32 * wr + fm) * 64 + swz];
                const halfx8 a1 = *(const halfx8*)&A_[(32 * wr + 16 + fm) * 64 + swz];
#pragma unroll
                for (int ct = 0; ct < 2; ++ct) {
                    const int ng = wc * 32 + ct * 16 + fm;
                    const halfx8 bg = *(const halfx8*)&B_[ng * 64 + swz];
                    const halfx8 bu = *(const halfx8*)&B_[(64 + ng) * 64 + swz];
                    accg[0][ct] = __builtin_amdgcn_mfma_f32_16x16x32_f16(a0, bg, accg[0][ct], 0, 0, 0);
                    accg[1][ct] = __builtin_amdgcn_mfma_f32_16x16x32_f16(a1, bg, accg[1][ct], 0, 0, 0);
                    accu[0][ct] = __builtin_amdgcn_mfma_f32_16x16x32_f16(a0, bu, accu[0][ct], 0, 0, 0);
                    accu[1][ct] = __builtin_amdgcn_mfma_f32_16x16x32_f16(a1, bu, accu[1][ct], 0, 0, 0);
                }
            }
        };

#pragma unroll
        for (int j = 0; j < 2; ++j) GLOAD16(aptr[j], a0l[j]);
#pragma unroll
        for (int j = 0; j < 4; ++j) GLOAD16(bptr[j], b0l[j]);
        __syncthreads();

        for (int kit = 0; kit < H_DIM / 64; kit += 2) {
            const int k1 = (kit + 1) * 64;
            if (k1 < H_DIM) {
#pragma unroll
                for (int j = 0; j < 2; ++j) GLOAD16(aptr[j] + k1, a1l[j]);
#pragma unroll
                for (int j = 0; j < 4; ++j) GLOAD16(bptr[j] + k1, b1l[j]);
            }
            mfma_phase(As0, Bs0);
            __syncthreads();
            const int k2 = (kit + 2) * 64;
            if (k2 < H_DIM) {
#pragma unroll
                for (int j = 0; j < 2; ++j) GLOAD16(aptr[j] + k2, a0l[j]);
#pragma unroll
                for (int j = 0; j < 4; ++j) GLOAD16(bptr[j] + k2, b0l[j]);
            }
            mfma_phase(As1, Bs1);
            __syncthreads();
        }

        // C/D layout: col = lane&15, row = q*4 + reg
#pragma unroll
        for (int rt = 0; rt < 2; ++rt)
#pragma unroll
            for (int r = 0; r < 4; ++r) {
                const int row = 32 * wr + 16 * rt + q * 4 + r;
                const int tk = toks[row];
                if (tk < 0) continue;
#pragma unroll
                for (int ct = 0; ct < 2; ++ct) {
                    const float g = accg[rt][ct][r];
                    const float u = accu[rt][ct][r];
                    const float s = g / (1.f + __expf(-g)) * u;
                    inter[(size_t)tk * I_DIM + n0 + wc * 32 + ct * 16 + fm] = (half_t)s;
                }
            }
        __syncthreads();   // toks/LDS reused next item
    }
    grid.sync();

    // ======================= Phase D: gemm2 =======================
    for (int it = bx; it < E_DIM * 8 * 64; it += NB) {
        const int e = it & 7;
        const int rest = it >> 3;
        const int n0 = (rest & 7) * 128;
        const int m0 = (rest >> 3) * 64;
        const int count = counts[e * CNT_STRIDE];
        if (m0 >= count) continue;

        if (tid < 64) {
            const int m = m0 + tid;
            toks[tid] = (m < count) ? tok_list[e * T_DIM + m] : -1;
        }
        __syncthreads();

        const half_t* De = downT + (size_t)e * H_DIM * I_DIM;

        const half_t* aptr[2]; const half_t* bptr[4];
        half_t *a0l[2], *a1l[2], *b0l[4], *b1l[4];
#pragma unroll
        for (int j = 0; j < 2; ++j) {
            const int r = w * 16 + j * 8 + lr;
            const int cg_ = lc ^ (r & 7);
            const int tk = toks[r];
            aptr[j] = inter + (size_t)(tk < 0 ? 0 : tk) * I_DIM + cg_ * 8;
            const int off = (w * 16 + j * 8) * 64;
            a0l[j] = As0 + off; a1l[j] = As1 + off;
        }
#pragma unroll
        for (int j = 0; j < 4; ++j) {
            const int n = w * 32 + j * 8 + lr;
            const int cg_ = lc ^ (n & 7);
            bptr[j] = De + (size_t)(n0 + n) * I_DIM + cg_ * 8;
            const int off = (w * 32 + j * 8) * 64;
            b0l[j] = Bs0 + off; b1l[j] = Bs1 + off;
        }

        floatx4 acc[2][4];
#pragma unroll
        for (int i = 0; i < 2; ++i)
#pragma unroll
            for (int j = 0; j < 4; ++j) acc[i][j] = fzero;

        auto mfma_phase2 = [&](const half_t* A_, const half_t* B_) {
#pragma unroll
            for (int ks = 0; ks < 2; ++ks) {
                const int swz = ((ks * 4 + q) ^ fm7) * 8;
                const halfx8 a0 = *(const halfx8*)&A_[(32 * wr + fm) * 64 + swz];
                const halfx8 a1 = *(const halfx8*)&A_[(32 * wr + 16 + fm) * 64 + swz];
#pragma unroll
                for (int ct = 0; ct < 4; ++ct) {
                    const halfx8 b = *(const halfx8*)&B_[(wc * 64 + ct * 16 + fm) * 64 + swz];
                    acc[0][ct] = __builtin_amdgcn_mfma_f32_16x16x32_f16(a0, b, acc[0][ct], 0, 0, 0);
                    acc[1][ct] = __builtin_amdgcn_mfma_f32_16x16x32_f16(a1, b, acc[1][ct], 0, 0, 0);
                }
            }
        };

#pragma unroll
        for (int j = 0; j < 2; ++j) GLOAD16(aptr[j], a0l[j]);
#pragma unroll
        for (int j = 0; j < 4; ++j) GLOAD16(bptr[j], b0l[j]);
        __syncthreads();

        for (int kit = 0; kit < I_DIM / 64; kit += 2) {
            const int k1 = (kit + 1) * 64;
            if (k1 < I_DIM) {
#pragma unroll
                for (int j = 0; j < 2; ++j) GLOAD16(aptr[j] + k1, a1l[j]);
#pragma unroll
                for (int j = 0; j < 4; ++j) GLOAD16(bptr[j] + k1, b1l[j]);
            }
            mfma_phase2(As0, Bs0);
            __syncthreads();
            const int k2 = (kit + 2) * 64;
            if (k2 < I_DIM) {
#pragma unroll
                for (int j = 0; j < 2; ++j) GLOAD16(aptr[j] + k2, a0l[j]);
#pragma unroll
                for (int j = 0; j < 4; ++j) GLOAD16(bptr[j] + k2, b0l[j]);
            }
            mfma_phase2(As1, Bs1);
            __syncthreads();
        }

#pragma unroll
        for (int rt = 0; rt < 2; ++rt)
#pragma unroll
            for (int r = 0; r < 4; ++r) {
                const int row = 32 * wr + 16 * rt + q * 4 + r;
                const int tk = toks[row];
                if (tk < 0) continue;
#pragma unroll
                for (int ct = 0; ct < 4; ++ct)
                    out[(size_t)tk * H_DIM + n0 + wc * 64 + ct * 16 + fm] = acc[rt][ct][r];
            }
        __syncthreads();
    }
}

// ---------------------------------------------------------------------------
extern "C" void kernel_launch(void* const* d_in, const int* in_sizes, int n_in,
                              void* d_out, int out_size, void* d_ws, size_t ws_size,
                              hipStream_t stream)
{
    const float* x         = (const float*)d_in[0];
    const int*   token_ids = (const int*)  d_in[1];
    const float* mu        = (const float*)d_in[2];
    const float* gup       = (const float*)d_in[3];
    const float* down      = (const float*)d_in[4];
    const float* mu_w      = (const float*)d_in[5];
    float* out = (float*)d_out;

    char* ws = (char*)d_ws;
    int*    counts    = (int*)(ws + OFF_COUNTS);
    int*    expert_id = (int*)(ws + OFF_EID);
    int*    tok_list  = (int*)(ws + OFF_TOKL);
    half_t* xb        = (half_t*)(ws + OFF_XB);
    half_t* gupT      = (half_t*)(ws + OFF_GUPT);
    half_t* downT     = (half_t*)(ws + OFF_DOWNT);
    half_t* inter     = (half_t*)(ws + OFF_INTER);

    void* kargs[] = {
        (void*)&x, (void*)&gup, (void*)&down, (void*)&mu,
        (void*)&token_ids, (void*)&mu_w,
        (void*)&xb, (void*)&gupT, (void*)&downT, (void*)&expert_id,
        (void*)&counts, (void*)&tok_list, (void*)&inter, (void*)&out
    };
    // 512 blocks = 2/CU (LDS 49.7KB <= 80KB) -> co-residency guaranteed.
    hipLaunchCooperativeKernel((const void*)fused_kernel,
                               dim3(512), dim3(256), kargs, 0, stream);
}

// Round 9
// 156.543 us; speedup vs baseline: 2.1647x; 2.1647x over previous
//
#include <hip/hip_runtime.h>
#include <cmath>

// Problem constants (fixed by the reference)
constexpr int T_DIM = 4096;
constexpr int H_DIM = 1024;
constexpr int E_DIM = 8;
constexpr int I_DIM = 512;   // 4096 / 8
constexpr int V_DIM = 32000;

typedef _Float16 half_t;
typedef __attribute__((ext_vector_type(8))) _Float16 halfx8;
typedef __attribute__((ext_vector_type(4))) _Float16 halfx4;
typedef __attribute__((ext_vector_type(4))) float floatx4;

// async global->LDS, 16 B per lane; LDS dest is wave-uniform base + lane*16
#define GLOAD16(g, l)                                                        \
    __builtin_amdgcn_global_load_lds(                                        \
        (const __attribute__((address_space(1))) void*)(g),                  \
        (__attribute__((address_space(3))) void*)(l), 16, 0, 0)

// ---------------------------------------------------------------------------
// Workspace layout (bytes)
// ---------------------------------------------------------------------------
constexpr int  CNT_STRIDE  = 16;                                          // ints
constexpr size_t OFF_COUNTS = 0;                                          // E*16 ints (512 B)
constexpr size_t OFF_EID    = 1024;                                       // T ints (16 KB)
constexpr size_t OFF_TOKL   = OFF_EID + (size_t)T_DIM * 4;                // E*T ints (128 KB)
constexpr size_t OFF_XB     = OFF_TOKL + (size_t)E_DIM * T_DIM * 4;       // T*H f16 (8 MB)
constexpr size_t OFF_GUPT   = OFF_XB + (size_t)T_DIM * H_DIM * 2;         // E*2I*H f16 (16 MB)
constexpr size_t OFF_DOWNT  = OFF_GUPT + (size_t)E_DIM * 2 * I_DIM * H_DIM * 2; // E*H*I f16 (8 MB)
constexpr size_t OFF_INTER  = OFF_DOWNT + (size_t)E_DIM * H_DIM * I_DIM * 2;    // T*I f16 (4 MB)

// ---------------------------------------------------------------------------
// R9 == R8 resubmitted (round-8 bench died on infra, not the kernel).
// Theory: R6's __syncthreads (= s_waitcnt vmcnt(0) + s_barrier) after each
// MFMA phase drains the just-issued prefetch — the guide's documented
// m97-ceiling stall — nullifying the dbuf. This keeps R6's 4-launch DAG and
// replaces only the K-loop sync with raw s_barrier + counted vmcnt(6) so the
// next stage's 6 loads stay in flight across the barrier (T4), with
// lgkmcnt(0)+sched_barrier(0) before the reuse-barrier (rule 18), fully
// unrolled (static buffer parity + wait immediates), setprio around MFMA (T5).
// ---------------------------------------------------------------------------
__global__ __launch_bounds__(256) void prep_kernel(
    const float* __restrict__ x, const float* __restrict__ gup,
    const float* __restrict__ mu, const int* __restrict__ token_ids,
    const float* __restrict__ mu_w, half_t* __restrict__ xb,
    half_t* __restrict__ gupT, int* __restrict__ expert_id)
{
    const int z = blockIdx.z, bx = blockIdx.x, by = blockIdx.y;
    const int tid = threadIdx.x;

    if (z >= 2) {  // routing logits: one block per token
        const int t = ((z - 2) * 256 + by) * 8 + bx;

        const float4 m = *(const float4*)&mu[(size_t)t * H_DIM + tid * 4];
        float acc[E_DIM];
#pragma unroll
        for (int e = 0; e < E_DIM; ++e) {
            const float4 w = *(const float4*)&mu_w[e * H_DIM + tid * 4];
            acc[e] = m.x * w.x + m.y * w.y + m.z * w.z + m.w * w.w;
        }
#pragma unroll
        for (int e = 0; e < E_DIM; ++e) {
#pragma unroll
            for (int off = 32; off > 0; off >>= 1)
                acc[e] += __shfl_down(acc[e], off, 64);
        }
        __shared__ float part[4][E_DIM];
        const int lane = tid & 63, w = tid >> 6;
        if (lane == 0) {
#pragma unroll
            for (int e = 0; e < E_DIM; ++e) part[w][e] = acc[e];
        }
        __syncthreads();
        if (tid == 0) {
            int tk = token_ids[t];
            tk = min(max(tk, 0), V_DIM - 1);
            const int be = tk & (E_DIM - 1);
            float best = -1e30f; int bi = 0;
#pragma unroll
            for (int e = 0; e < E_DIM; ++e) {
                const float c = part[0][e] + part[1][e] + part[2][e] + part[3][e]
                              + (e == be ? 10.f : 0.f);
                if (c > best) { best = c; bi = e; }  // strict > = first max (jnp.argmax)
            }
            expert_id[t] = bi;
        }
        return;
    }

    if (z == 1) {  // convert x -> f16: 512 blocks x 8192 floats (4 x 2048)
        const int idx = by * 8 + bx;
        if (idx >= 512) return;
#pragma unroll
        for (int p = 0; p < 4; ++p) {
            const size_t i = (size_t)idx * 8192 + p * 2048 + tid * 8;
            const float4 v0 = *(const float4*)&x[i];
            const float4 v1 = *(const float4*)&x[i + 4];
            halfx8 h = { (half_t)v0.x, (half_t)v0.y, (half_t)v0.z, (half_t)v0.w,
                         (half_t)v1.x, (half_t)v1.y, (half_t)v1.z, (half_t)v1.w };
            *(halfx8*)&xb[i] = h;
        }
        return;
    }

    // z == 0: gup transpose, e = bx (== XCD). K = H = 1024, N = 2I = 1024.
    __shared__ float tile[64][65];
    const float* se = gup + (size_t)bx * H_DIM * (2 * I_DIM);
    half_t* de = gupT + (size_t)bx * (2 * I_DIM) * H_DIM;
    constexpr int N = 1024, K = H_DIM;
    const int n0 = (by & 15) * 64, k0 = (by >> 4) * 64;
    const int c4 = (tid & 15) * 4, r0 = tid >> 4;
#pragma unroll
    for (int p = 0; p < 4; ++p) {
        const int r = r0 + p * 16;
        const float4 v = *(const float4*)&se[(size_t)(k0 + r) * N + n0 + c4];
        tile[r][c4 + 0] = v.x; tile[r][c4 + 1] = v.y;
        tile[r][c4 + 2] = v.z; tile[r][c4 + 3] = v.w;
    }
    __syncthreads();
#pragma unroll
    for (int p = 0; p < 4; ++p) {
        const int n = r0 + p * 16;
        const int kc = c4;
        halfx4 h = { (half_t)tile[kc + 0][n], (half_t)tile[kc + 1][n],
                     (half_t)tile[kc + 2][n], (half_t)tile[kc + 3][n] };
        *(halfx4*)&de[(size_t)(n0 + n) * K + k0 + kc] = h;
    }
}

// ---------------------------------------------------------------------------
// Scatter, zero-atomic (R5 win): one block per expert, 1024 threads.
// ---------------------------------------------------------------------------
__global__ __launch_bounds__(1024) void scatter_kernel(
    const int* __restrict__ expert_id, int* __restrict__ counts,
    int* __restrict__ tok_list)
{
    const int e = blockIdx.x;
    const int tid = threadIdx.x;
    const int lane = tid & 63, wv = tid >> 6;   // 16 waves
    __shared__ int wcnt[16];
    int base = 0;
#pragma unroll
    for (int r = 0; r < 4; ++r) {
        const int t = r * 1024 + tid;
        const bool m = (expert_id[t] == e);
        const unsigned long long mask = __ballot(m);
        const int wrank = (int)__popcll(mask & ((1ull << lane) - 1ull));
        if (lane == 0) wcnt[wv] = (int)__popcll(mask);
        __syncthreads();
        int pre = 0, tot = 0;
#pragma unroll
        for (int i = 0; i < 16; ++i) {
            const int c = wcnt[i];
            pre += (i < wv) ? c : 0;
            tot += c;
        }
        if (m) tok_list[e * T_DIM + base + pre + wrank] = t;
        base += tot;
        __syncthreads();   // wcnt reused next round
    }
    if (tid == 0) counts[e * CNT_STRIDE] = base;
}

// ---------------------------------------------------------------------------
// MFMA GEMM 1: inter = silu(x@Wg) * (x@Wu). Tile 64 tok x (64g + 64u), BK=64,
// dbuf + COUNTED-VMCNT pipeline. 6 gload_lds per thread per stage =>
// vmcnt(6) at iter start guarantees the CURRENT buffer landed while the next
// stage's 6 loads stay in flight across the barrier (never vmcnt(0) mid-loop).
// blockIdx.x = expert -> XCD affinity. z in [64,80) = down-proj transpose.
// ---------------------------------------------------------------------------
__global__ __launch_bounds__(256) void gemm1_mfma_kernel(
    const half_t* __restrict__ xb, const half_t* __restrict__ gupT,
    const float* __restrict__ down, half_t* __restrict__ downT,
    const int* __restrict__ counts, const int* __restrict__ tok_list,
    half_t* __restrict__ inter)
{
    // As0 | As1 | Bs0 | Bs1 | toks  = 8K+8K+16K+16K+256
    __shared__ __align__(16) char smraw[49152 + 64 * 4];
    const int tid = threadIdx.x;
    const int e = blockIdx.x;              // expert == XCD affinity

    if (blockIdx.z >= 64) {  // down transpose: K = I = 512, N = H = 1024
        float (*tile)[65] = (float (*)[65])smraw;   // 16.6KB
        const float* se = down + (size_t)e * I_DIM * H_DIM;
        half_t* de = downT + (size_t)e * H_DIM * I_DIM;
        const int n0 = (blockIdx.z - 64) * 64, k0 = blockIdx.y * 64;
        const int c4 = (tid & 15) * 4, r0 = tid >> 4;
#pragma unroll
        for (int p = 0; p < 4; ++p) {
            const int r = r0 + p * 16;
            const float4 v = *(const float4*)&se[(size_t)(k0 + r) * H_DIM + n0 + c4];
            tile[r][c4 + 0] = v.x; tile[r][c4 + 1] = v.y;
            tile[r][c4 + 2] = v.z; tile[r][c4 + 3] = v.w;
        }
        __syncthreads();
#pragma unroll
        for (int p = 0; p < 4; ++p) {
            const int n = r0 + p * 16;
            const int kc = c4;
            halfx4 h = { (half_t)tile[kc + 0][n], (half_t)tile[kc + 1][n],
                         (half_t)tile[kc + 2][n], (half_t)tile[kc + 3][n] };
            *(halfx4*)&de[(size_t)(n0 + n) * I_DIM + k0 + kc] = h;
        }
        return;
    }

    const int count = counts[e * CNT_STRIDE];
    const int m0 = blockIdx.z * 64;
    if (m0 >= count) return;
    const int n0 = blockIdx.y * 64;        // gate col block

    half_t* const As0 = (half_t*)smraw;                     // 64x64
    half_t* const As1 = (half_t*)(smraw + 8192);
    half_t* const Bs0 = (half_t*)(smraw + 16384);           // 128x64
    half_t* const Bs1 = (half_t*)(smraw + 32768);
    int* const toks = (int*)(smraw + 49152);

    if (tid < 64) {
        const int m = m0 + tid;
        toks[tid] = (m < count) ? tok_list[e * T_DIM + m] : -1;
    }
    __syncthreads();

    const half_t* We = gupT + (size_t)e * (2 * I_DIM) * H_DIM;

    const int lane = tid & 63;
    const int w = tid >> 6;
    const int lr = lane >> 3, lc = lane & 7;

    const half_t* aptr[2]; const half_t* bptr[4];
    half_t *a0l[2], *a1l[2], *b0l[4], *b1l[4];
#pragma unroll
    for (int j = 0; j < 2; ++j) {                 // A rows [w*16, w*16+16)
        const int r = w * 16 + j * 8 + lr;
        const int cg = lc ^ (r & 7);
        const int tk = toks[r];
        aptr[j] = xb + (size_t)(tk < 0 ? 0 : tk) * H_DIM + cg * 8;
        const int off = (w * 16 + j * 8) * 64;
        a0l[j] = As0 + off; a1l[j] = As1 + off;
    }
#pragma unroll
    for (int j = 0; j < 4; ++j) {                 // B rows [w*32, w*32+32)
        const int n = w * 32 + j * 8 + lr;
        const int col = (n < 64) ? (n0 + n) : (I_DIM + n0 + (n - 64));
        const int cg = lc ^ (n & 7);
        bptr[j] = We + (size_t)col * H_DIM + cg * 8;
        const int off = (w * 32 + j * 8) * 64;
        b0l[j] = Bs0 + off; b1l[j] = Bs1 + off;
    }

    const floatx4 fzero = {0.f, 0.f, 0.f, 0.f};
    floatx4 accg[2][2], accu[2][2];
#pragma unroll
    for (int i = 0; i < 2; ++i)
#pragma unroll
        for (int j = 0; j < 2; ++j) { accg[i][j] = fzero; accu[i][j] = fzero; }

    const int wr = w >> 1, wc = w & 1;
    const int fm = lane & 15, q = lane >> 4;
    const int fm7 = fm & 7;

    auto mfma_phase = [&](const half_t* A_, const half_t* B_) {
#pragma unroll
        for (int ks = 0; ks < 2; ++ks) {
            const int swz = ((ks * 4 + q) ^ fm7) * 8;   // halves
            const halfx8 a0 = *(const halfx8*)&A_[(32 * wr + fm) * 64 + swz];
            const halfx8 a1 = *(const halfx8*)&A_[(32 * wr + 16 + fm) * 64 + swz];
#pragma unroll
            for (int ct = 0; ct < 2; ++ct) {
                const int ng = wc * 32 + ct * 16 + fm;
                const halfx8 bg = *(const halfx8*)&B_[ng * 64 + swz];
                const halfx8 bu = *(const halfx8*)&B_[(64 + ng) * 64 + swz];
                accg[0][ct] = __builtin_amdgcn_mfma_f32_16x16x32_f16(a0, bg, accg[0][ct], 0, 0, 0);
                accg[1][ct] = __builtin_amdgcn_mfma_f32_16x16x32_f16(a1, bg, accg[1][ct], 0, 0, 0);
                accu[0][ct] = __builtin_amdgcn_mfma_f32_16x16x32_f16(a0, bu, accu[0][ct], 0, 0, 0);
                accu[1][ct] = __builtin_amdgcn_mfma_f32_16x16x32_f16(a1, bu, accu[1][ct], 0, 0, 0);
            }
        }
    };

    // prologue: stage k0 -> buf0, k1 -> buf1 (12 outstanding, NOT drained)
#pragma unroll
    for (int j = 0; j < 2; ++j) GLOAD16(aptr[j], a0l[j]);
#pragma unroll
    for (int j = 0; j < 4; ++j) GLOAD16(bptr[j], b0l[j]);
#pragma unroll
    for (int j = 0; j < 2; ++j) GLOAD16(aptr[j] + 64, a1l[j]);
#pragma unroll
    for (int j = 0; j < 4; ++j) GLOAD16(bptr[j] + 64, b1l[j]);

    constexpr int NSTEP1 = H_DIM / 64;   // 16
#pragma unroll
    for (int it = 0; it < NSTEP1; ++it) {
        // vmcnt(6): all but the newest 6 (next stage) retired => buf[it&1] landed
        if (it < NSTEP1 - 1) asm volatile("s_waitcnt vmcnt(6)" ::: "memory");
        else                 asm volatile("s_waitcnt vmcnt(0)" ::: "memory");
        __builtin_amdgcn_s_barrier();
        __builtin_amdgcn_sched_barrier(0);
        __builtin_amdgcn_s_setprio(1);
        if ((it & 1) == 0) mfma_phase(As0, Bs0);
        else               mfma_phase(As1, Bs1);
        __builtin_amdgcn_s_setprio(0);
        asm volatile("s_waitcnt lgkmcnt(0)" ::: "memory");  // my ds_reads retired
        __builtin_amdgcn_sched_barrier(0);
        __builtin_amdgcn_s_barrier();                       // all waves done reading
        __builtin_amdgcn_sched_barrier(0);
        const int k2 = (it + 2) * 64;
        if (k2 < H_DIM) {                 // re-stage the buffer just consumed
            if ((it & 1) == 0) {
#pragma unroll
                for (int j = 0; j < 2; ++j) GLOAD16(aptr[j] + k2, a0l[j]);
#pragma unroll
                for (int j = 0; j < 4; ++j) GLOAD16(bptr[j] + k2, b0l[j]);
            } else {
#pragma unroll
                for (int j = 0; j < 2; ++j) GLOAD16(aptr[j] + k2, a1l[j]);
#pragma unroll
                for (int j = 0; j < 4; ++j) GLOAD16(bptr[j] + k2, b1l[j]);
            }
        }
    }

    // C/D layout: col = lane&15, row = q*4 + reg
#pragma unroll
    for (int rt = 0; rt < 2; ++rt)
#pragma unroll
        for (int r = 0; r < 4; ++r) {
            const int row = 32 * wr + 16 * rt + q * 4 + r;
            const int tk = toks[row];
            if (tk < 0) continue;
#pragma unroll
            for (int ct = 0; ct < 2; ++ct) {
                const float g = accg[rt][ct][r];
                const float u = accu[rt][ct][r];
                const float s = g / (1.f + __expf(-g)) * u;
                inter[(size_t)tk * I_DIM + n0 + wc * 32 + ct * 16 + fm] = (half_t)s;
            }
        }
}

// ---------------------------------------------------------------------------
// MFMA GEMM 2: out = inter @ down. Tile 64 x 128, same counted-vmcnt pipeline
// (8 K-steps). Same expert==blockIdx.x XCD-affinity grid.
// ---------------------------------------------------------------------------
__global__ __launch_bounds__(256) void gemm2_mfma_kernel(
    const half_t* __restrict__ inter, const half_t* __restrict__ downT,
    const int* __restrict__ counts, const int* __restrict__ tok_list,
    float* __restrict__ out)
{
    const int e = blockIdx.x;              // expert == XCD affinity
    const int count = counts[e * CNT_STRIDE];
    const int m0 = blockIdx.z * 64;
    if (m0 >= count) return;
    const int n0 = blockIdx.y * 128;

    __shared__ __align__(16) char smraw[49152 + 64 * 4];
    half_t* const As0 = (half_t*)smraw;
    half_t* const As1 = (half_t*)(smraw + 8192);
    half_t* const Bs0 = (half_t*)(smraw + 16384);
    half_t* const Bs1 = (half_t*)(smraw + 32768);
    int* const toks = (int*)(smraw + 49152);

    const int tid = threadIdx.x;
    if (tid < 64) {
        const int m = m0 + tid;
        toks[tid] = (m < count) ? tok_list[e * T_DIM + m] : -1;
    }
    __syncthreads();

    const half_t* De = downT + (size_t)e * H_DIM * I_DIM;

    const int lane = tid & 63;
    const int w = tid >> 6;
    const int lr = lane >> 3, lc = lane & 7;

    const half_t* aptr[2]; const half_t* bptr[4];
    half_t *a0l[2], *a1l[2], *b0l[4], *b1l[4];
#pragma unroll
    for (int j = 0; j < 2; ++j) {
        const int r = w * 16 + j * 8 + lr;
        const int cg = lc ^ (r & 7);
        const int tk = toks[r];
        aptr[j] = inter + (size_t)(tk < 0 ? 0 : tk) * I_DIM + cg * 8;
        const int off = (w * 16 + j * 8) * 64;
        a0l[j] = As0 + off; a1l[j] = As1 + off;
    }
#pragma unroll
    for (int j = 0; j < 4; ++j) {
        const int n = w * 32 + j * 8 + lr;
        const int cg = lc ^ (n & 7);
        bptr[j] = De + (size_t)(n0 + n) * I_DIM + cg * 8;
        const int off = (w * 32 + j * 8) * 64;
        b0l[j] = Bs0 + off; b1l[j] = Bs1 + off;
    }

    const floatx4 fzero = {0.f, 0.f, 0.f, 0.f};
    floatx4 acc[2][4];
#pragma unroll
    for (int i = 0; i < 2; ++i)
#pragma unroll
        for (int j = 0; j < 4; ++j) acc[i][j] = fzero;

    const int wr = w >> 1, wc = w & 1;
    const int fm = lane & 15, q = lane >> 4;
    const int fm7 = fm & 7;

    auto mfma_phase = [&](const half_t* A_, const half_t* B_) {
#pragma unroll
        for (int ks = 0; ks < 2; ++ks) {
            const int swz = ((ks * 4 + q) ^ fm7) * 8;
            const halfx8 a0 = *(const halfx8*)&A_[(32 * wr + fm) * 64 + swz];
            const halfx8 a1 = *(const halfx8*)&A_[(32 * wr + 16 + fm) * 64 + swz];
#pragma unroll
            for (int ct = 0; ct < 4; ++ct) {
                const halfx8 b = *(const halfx8*)&B_[(wc * 64 + ct * 16 + fm) * 64 + swz];
                acc[0][ct] = __builtin_amdgcn_mfma_f32_16x16x32_f16(a0, b, acc[0][ct], 0, 0, 0);
                acc[1][ct] = __builtin_amdgcn_mfma_f32_16x16x32_f16(a1, b, acc[1][ct], 0, 0, 0);
            }
        }
    };

    // prologue: stage k0 -> buf0, k1 -> buf1
#pragma unroll
    for (int j = 0; j < 2; ++j) GLOAD16(aptr[j], a0l[j]);
#pragma unroll
    for (int j = 0; j < 4; ++j) GLOAD16(bptr[j], b0l[j]);
#pragma unroll
    for (int j = 0; j < 2; ++j) GLOAD16(aptr[j] + 64, a1l[j]);
#pragma unroll
    for (int j = 0; j < 4; ++j) GLOAD16(bptr[j] + 64, b1l[j]);

    constexpr int NSTEP2 = I_DIM / 64;   // 8
#pragma unroll
    for (int it = 0; it < NSTEP2; ++it) {
        if (it < NSTEP2 - 1) asm volatile("s_waitcnt vmcnt(6)" ::: "memory");
        else                 asm volatile("s_waitcnt vmcnt(0)" ::: "memory");
        __builtin_amdgcn_s_barrier();
        __builtin_amdgcn_sched_barrier(0);
        __builtin_amdgcn_s_setprio(1);
        if ((it & 1) == 0) mfma_phase(As0, Bs0);
        else               mfma_phase(As1, Bs1);
        __builtin_amdgcn_s_setprio(0);
        asm volatile("s_waitcnt lgkmcnt(0)" ::: "memory");
        __builtin_amdgcn_sched_barrier(0);
        __builtin_amdgcn_s_barrier();
        __builtin_amdgcn_sched_barrier(0);
        const int k2 = (it + 2) * 64;
        if (k2 < I_DIM) {
            if ((it & 1) == 0) {
#pragma unroll
                for (int j = 0; j < 2; ++j) GLOAD16(aptr[j] + k2, a0l[j]);
#pragma unroll
                for (int j = 0; j < 4; ++j) GLOAD16(bptr[j] + k2, b0l[j]);
            } else {
#pragma unroll
                for (int j = 0; j < 2; ++j) GLOAD16(aptr[j] + k2, a1l[j]);
#pragma unroll
                for (int j = 0; j < 4; ++j) GLOAD16(bptr[j] + k2, b1l[j]);
            }
        }
    }

#pragma unroll
    for (int rt = 0; rt < 2; ++rt)
#pragma unroll
        for (int r = 0; r < 4; ++r) {
            const int row = 32 * wr + 16 * rt + q * 4 + r;
            const int tk = toks[row];
            if (tk < 0) continue;
#pragma unroll
            for (int ct = 0; ct < 4; ++ct)
                out[(size_t)tk * H_DIM + n0 + wc * 64 + ct * 16 + fm] = acc[rt][ct][r];
        }
}

// ---------------------------------------------------------------------------
extern "C" void kernel_launch(void* const* d_in, const int* in_sizes, int n_in,
                              void* d_out, int out_size, void* d_ws, size_t ws_size,
                              hipStream_t stream)
{
    const float* x         = (const float*)d_in[0];
    const int*   token_ids = (const int*)  d_in[1];
    const float* mu        = (const float*)d_in[2];
    const float* gup       = (const float*)d_in[3];
    const float* down      = (const float*)d_in[4];
    const float* mu_w      = (const float*)d_in[5];
    float* out = (float*)d_out;

    char* ws = (char*)d_ws;
    int*    counts    = (int*)(ws + OFF_COUNTS);
    int*    expert_id = (int*)(ws + OFF_EID);
    int*    tok_list  = (int*)(ws + OFF_TOKL);
    half_t* xb        = (half_t*)(ws + OFF_XB);
    half_t* gupT      = (half_t*)(ws + OFF_GUPT);
    half_t* downT     = (half_t*)(ws + OFF_DOWNT);
    half_t* inter     = (half_t*)(ws + OFF_INTER);

    // grid (8,256,4): bx == XCD. z=0: gup transpose. z=1: x->f16.
    // z=2..3: routing (1 block/token).
    prep_kernel<<<dim3(8, 256, 4), 256, 0, stream>>>(
        x, gup, mu, token_ids, mu_w, xb, gupT, expert_id);
    // zero-atomic scatter: one block per expert.
    scatter_kernel<<<E_DIM, 1024, 0, stream>>>(expert_id, counts, tok_list);
    // z<64: gemm m-blocks (early-exit past count); z in [64,80): down-proj
    // transpose tiles overlapped with the gemm.
    gemm1_mfma_kernel<<<dim3(E_DIM, 8, 80), 256, 0, stream>>>(
        xb, gupT, down, downT, counts, tok_list, inter);
    gemm2_mfma_kernel<<<dim3(E_DIM, 8, T_DIM / 64), 256, 0, stream>>>(
        inter, downT, counts, tok_list, out);
}